// Round 6
// baseline (98.262 us; speedup 1.0000x reference)
//
#include <hip/hip_runtime.h>
#include <hip/hip_bf16.h>
#include <cstdint>

#define FLT 32
#define TOUT 505
#define TT 2048
#define MROWS 16384
#define QROWS 4040                 // 8*505
#define KDIM 512
#define BK 64
#define NT 8                       // KDIM/BK
#define BM 256
#define BN 256

typedef float f32x4 __attribute__((ext_vector_type(4)));
typedef __bf16 bf16x8 __attribute__((ext_vector_type(8)));

static __device__ __forceinline__ ushort f2bf(float f) {
  uint32_t u = __float_as_uint(f);
  uint32_t r = (u + 0x7fffu + ((u >> 16) & 1u)) >> 16;
  return (ushort)r;
}
static __device__ __forceinline__ float bf2f(ushort h) {
  return __uint_as_float(((uint32_t)h) << 16);
}

// ---------------- fused prep: x->bf16 cast + W transpose/cast + bias --------
__global__ void prep_kernel(const float* __restrict__ x,
                            const float* __restrict__ Wq, const float* __restrict__ Wk,
                            const float* __restrict__ Wv, const float* __restrict__ bq,
                            const float* __restrict__ bk, const float* __restrict__ bv,
                            ushort* __restrict__ xb, ushort* __restrict__ wt,
                            float* __restrict__ bias) {
  const int bid = blockIdx.x;
  if (bid < 8192) {                       // x cast: 4 floats / thread
    int i = bid * 256 + threadIdx.x;
    float4 v = reinterpret_cast<const float4*>(x)[i];
    ushort4 o;
    o.x = f2bf(v.x); o.y = f2bf(v.y); o.z = f2bf(v.z); o.w = f2bf(v.w);
    reinterpret_cast<ushort4*>(xb)[i] = o;
  } else {                                // W -> Wt[N][K] bf16, 16B writes
    int idx = (bid - 8192) * 256 + threadIdx.x;
    const int NG = 1536 * 512 / 8;        // 98304
    if (idx < NG) {
      int n = idx >> 6;
      int k0 = (idx & 63) * 8;
      const float* W = (n < 512) ? Wq : (n < 1024) ? Wk : Wv;
      int nn = n & 511;
      ushort v8[8];
      #pragma unroll
      for (int e = 0; e < 8; ++e) v8[e] = f2bf(W[(size_t)(k0 + e) * 512 + nn]);
      *reinterpret_cast<uint4*>(&wt[(size_t)n * 512 + k0]) =
          *reinterpret_cast<const uint4*>(v8);
    } else {
      int n = idx - NG;
      if (n < 1536) {
        const float* bsrc = (n < 512) ? bq : (n < 1024) ? bk : bv;
        bias[n] = bsrc[n & 511];
      }
    }
  }
}

// ---------------- GEMM: 256^2, 8 waves, dbuf; q-blocks first, kv 1 round ----
// bid 0..31:   qc[4096][512] = gather(xb) @ Wq^T + bq   (M-tiles 16, N-tiles 2)
// bid 32..287: kv[16384][1024] = xb @ [Wk|Wv]^T + b     (M-tiles 64, N-tiles 4)
__global__ __launch_bounds__(512, 2) void gemm_kernel(
    const ushort* __restrict__ xb, const ushort* __restrict__ wt,
    const float* __restrict__ bias, ushort* __restrict__ kv, ushort* __restrict__ qc) {
  extern __shared__ ushort smem[];        // 128 KB: A[2]@0,32K ; B[2]@64K,96K

  const int tid = threadIdx.x;
  const int lane = tid & 63;
  const int wv = tid >> 6;                // 0..7
  const int wr = wv >> 2;                 // 0..1  (M half)
  const int wc = wv & 3;                  // 0..3  (N quarter)
  const int fr = lane & 15;
  const int fq = lane >> 4;
  const int bid = blockIdx.x;

  int m0, n0, ost, gather;
  const ushort* wtb;
  const float* biasb;
  ushort* outp;
  if (bid >= 32) {                        // kv partition: 256 blocks, 1 round
    int l = bid - 32;                     // XCD = bid%8 = l%8
    int xcd = l & 7, j = l >> 3;          // j in [0,32)
    m0 = (8 * xcd + (j >> 2)) * BM;       // XCD x owns batch x's rows
    n0 = (j & 3) * BN;
    wtb = wt + (size_t)512 * KDIM; biasb = bias + 512;
    outp = kv; ost = 1024; gather = 0;
  } else {                                // q partition: 32 half-size blocks
    int l = bid;
    m0 = (2 * (l & 7) + (l >> 4)) * BM;
    n0 = ((l >> 3) & 1) * BN;
    wtb = wt; biasb = bias;
    outp = qc; ost = 512; gather = 1;
  }

  char* const AbB = (char*)smem;          // A: buf*32768
  char* const BbB = (char*)smem + 65536;  // B: buf*32768

  // staging sources: linear LDS dest, inverse-swizzled source column
  const ushort* aSrc[4];
  const ushort* bSrc[4];
  #pragma unroll
  for (int i = 0; i < 4; ++i) {
    int idx = i * 512 + tid;              // 0..2047
    int row = idx >> 3;                   // 0..255
    int slot = idx & 7;                   // 16B slot in 128B row
    int scol = ((slot * 16) ^ ((row & 7) << 4)) >> 1;
    size_t arow;
    if (gather) {
      int r = m0 + row;
      if (r > QROWS - 1) r = QROWS - 1;
      int bb = r / TOUT;
      int t2 = r - bb * TOUT;
      arow = (size_t)bb * TT + (size_t)t2 * 4 + FLT / 2;
    } else {
      arow = (size_t)(m0 + row);
    }
    aSrc[i] = xb + arow * KDIM + scol;
    bSrc[i] = wtb + (size_t)(n0 + row) * KDIM + scol;
  }

#define STAGE(T, BUF) do {                                                        \
    const int koff = (T) * BK;                                                    \
    _Pragma("unroll")                                                             \
    for (int i = 0; i < 4; ++i) {                                                 \
      int ldst = (BUF) * 32768 + i * 8192 + tid * 16;                             \
      __builtin_amdgcn_global_load_lds(                                           \
          (const __attribute__((address_space(1))) unsigned int*)(aSrc[i] + koff),\
          (__attribute__((address_space(3))) unsigned int*)(AbB + ldst),          \
          16, 0, 0);                                                              \
      __builtin_amdgcn_global_load_lds(                                           \
          (const __attribute__((address_space(1))) unsigned int*)(bSrc[i] + koff),\
          (__attribute__((address_space(3))) unsigned int*)(BbB + ldst),          \
          16, 0, 0);                                                              \
    }                                                                             \
  } while (0)

  f32x4 acc[8][4];
  #pragma unroll
  for (int i = 0; i < 8; ++i)
    #pragma unroll
    for (int j = 0; j < 4; ++j) acc[i][j] = (f32x4){0.f, 0.f, 0.f, 0.f};

  STAGE(0, 0);
  __syncthreads();                        // drains prologue stage
  for (int t = 0; t < NT; ++t) {
    const int cur = t & 1;
    if (t < NT - 1) STAGE(t + 1, cur ^ 1);
    __builtin_amdgcn_sched_barrier(0);    // pin stage-issue before compute
    const char* Ab = AbB + cur * 32768;
    const char* Bb = BbB + cur * 32768;
    __builtin_amdgcn_s_setprio(1);
    #pragma unroll
    for (int ks = 0; ks < 2; ++ks) {
      const int cab = ks * 64 + fq * 16;  // byte col within 128B row
      bf16x8 bg[4];
      #pragma unroll
      for (int j = 0; j < 4; ++j) {
        int rb = wc * 64 + j * 16 + fr;
        bg[j] = *reinterpret_cast<const bf16x8*>(Bb + rb * 128 + (cab ^ ((rb & 7) << 4)));
      }
      #pragma unroll
      for (int h = 0; h < 2; ++h) {
        bf16x8 af[4];
        #pragma unroll
        for (int i2 = 0; i2 < 4; ++i2) {
          int ra = wr * 128 + (h * 4 + i2) * 16 + fr;
          af[i2] = *reinterpret_cast<const bf16x8*>(Ab + ra * 128 + (cab ^ ((ra & 7) << 4)));
        }
        #pragma unroll
        for (int i2 = 0; i2 < 4; ++i2)
          #pragma unroll
          for (int j = 0; j < 4; ++j)
            acc[h * 4 + i2][j] =
                __builtin_amdgcn_mfma_f32_16x16x32_bf16(af[i2], bg[j], acc[h * 4 + i2][j], 0, 0, 0);
      }
    }
    __builtin_amdgcn_s_setprio(0);
    __syncthreads();                      // one drain per K-step, under MFMA cover
  }
#undef STAGE

  // epilogue: bias + bf16 store.  D: row=(lane>>4)*4+r, col=lane&15
  #pragma unroll
  for (int j = 0; j < 4; ++j) {
    int col = n0 + wc * 64 + j * 16 + fr;
    float bvl = biasb[col];
    #pragma unroll
    for (int i = 0; i < 8; ++i) {
      int rowb = m0 + wr * 128 + i * 16 + fq * 4;
      #pragma unroll
      for (int r = 0; r < 4; ++r) {
        if (!gather || (rowb + r) < QROWS)
          outp[(size_t)(rowb + r) * ost + col] = f2bf(acc[i][j][r] + bvl);
      }
    }
  }
}

// ---------------- windowed attention (R2-proven) ----------------
__global__ __launch_bounds__(256) void attn_kernel(
    const ushort* __restrict__ kv,   // [MROWS][1024] bf16: [k|v]
    const ushort* __restrict__ qc,   // [QROWS][512] bf16 (center q rows)
    float* __restrict__ out) {
  __shared__ float q_lds[KDIM];
  __shared__ float s_lds[FLT];
  __shared__ float p_lds[FLT];

  const int bid = blockIdx.x;
  const int b = bid & 7;                  // batch pinned to XCD (matches gemm)
  const int t = bid >> 3;
  const size_t base_row = (size_t)b * TT + (size_t)t * 4;
  const int tid = threadIdx.x;
  const int lane = tid & 63;
  const int wv = tid >> 6;

  {
    const ushort* qrow = qc + ((size_t)b * TOUT + t) * KDIM;
    uint v = *reinterpret_cast<const uint*>(qrow + tid * 2);
    q_lds[tid * 2]     = bf2f((ushort)(v & 0xffffu));
    q_lds[tid * 2 + 1] = bf2f((ushort)(v >> 16));
  }
  __syncthreads();

  // scores: 8 lanes per filter tap
  const int fl = lane >> 3;
  const int f = wv * 8 + fl;
  const int sub = lane & 7;
  const ushort* krow = kv + (base_row + f) * 1024;
  float acc = 0.f;
  #pragma unroll
  for (int j = 0; j < 8; ++j) {
    int d = (j * 8 + sub) * 8;
    uint4 kv4 = *reinterpret_cast<const uint4*>(krow + d);
    const ushort* ks = reinterpret_cast<const ushort*>(&kv4);
    #pragma unroll
    for (int e = 0; e < 8; ++e) acc += q_lds[d + e] * bf2f(ks[e]);
  }
  acc += __shfl_xor(acc, 1);
  acc += __shfl_xor(acc, 2);
  acc += __shfl_xor(acc, 4);
  if (sub == 0) s_lds[f] = acc * 0.04419417382415922f;  // 1/sqrt(512)
  __syncthreads();

  float m = -1e30f;
  #pragma unroll
  for (int i = 0; i < FLT; ++i) m = fmaxf(m, s_lds[i]);
  if (tid < FLT) p_lds[tid] = __expf(s_lds[tid] - m);
  __syncthreads();
  float sum = 0.f;
  #pragma unroll
  for (int i = 0; i < FLT; ++i) sum += p_lds[i];
  const float inv = 1.f / sum;

  const int d = tid * 2;
  float o0 = 0.f, o1 = 0.f;
  const ushort* vbase = kv + base_row * 1024 + 512 + d;
  #pragma unroll
  for (int ff = 0; ff < FLT; ++ff) {
    uint vvv = *reinterpret_cast<const uint*>(vbase + (size_t)ff * 1024);
    float w = p_lds[ff] * inv;
    o0 += w * bf2f((ushort)(vvv & 0xffffu));
    o1 += w * bf2f((ushort)(vvv >> 16));
  }
  float2* op = reinterpret_cast<float2*>(out + ((size_t)b * TOUT + t) * 512 + d);
  *op = make_float2(o0, o1);
}

// ---------------- launch ----------------
extern "C" void kernel_launch(void* const* d_in, const int* in_sizes, int n_in,
                              void* d_out, int out_size, void* d_ws, size_t ws_size,
                              hipStream_t stream) {
  const float* x  = (const float*)d_in[0];
  const float* Wq = (const float*)d_in[1];
  const float* bq = (const float*)d_in[2];
  const float* Wk = (const float*)d_in[3];
  const float* bk = (const float*)d_in[4];
  const float* Wv = (const float*)d_in[5];
  const float* bv = (const float*)d_in[6];
  float* out = (float*)d_out;

  char* ws = (char*)d_ws;
  ushort* xb   = (ushort*)ws;                                    // 16 MiB
  ushort* wt   = (ushort*)(ws + 16777216);                       // 1.5 MiB
  float*  bias = (float*)(ws + 16777216 + 1572864);              // 8 KiB
  ushort* kvb  = (ushort*)(ws + 18358272);                       // 32 MiB
  ushort* qc   = (ushort*)(ws + 18358272 + 33554432);            // 4 MiB (4096 rows)

  hipFuncSetAttribute((const void*)gemm_kernel,
                      hipFuncAttributeMaxDynamicSharedMemorySize, 131072);

  hipLaunchKernelGGL(prep_kernel, dim3(8192 + 390), dim3(256), 0, stream,
                     x, Wq, Wk, Wv, bq, bk, bv, xb, wt, bias);
  hipLaunchKernelGGL(gemm_kernel, dim3(288), dim3(512), 131072, stream,
                     xb, wt, bias, kvb, qc);
  hipLaunchKernelGGL(attn_kernel, dim3(QROWS), dim3(256), 0, stream, kvb, qc, out);
}

// Round 7
// 72.131 us; speedup vs baseline: 1.3623x; 1.3623x over previous
//
#include <hip/hip_runtime.h>
#include <hip/hip_bf16.h>
#include <cstdint>

#define FLT 32
#define TOUT 505
#define TT 2048
#define MROWS 16384
#define QROWS 4040                 // 8*505
#define KDIM 512
#define BK 64
#define NT 8                       // KDIM/BK

typedef float f32x4 __attribute__((ext_vector_type(4)));
typedef __bf16 bf16x8 __attribute__((ext_vector_type(8)));

static __device__ __forceinline__ ushort f2bf(float f) {
  uint32_t u = __float_as_uint(f);
  uint32_t r = (u + 0x7fffu + ((u >> 16) & 1u)) >> 16;
  return (ushort)r;
}
static __device__ __forceinline__ float bf2f(ushort h) {
  return __uint_as_float(((uint32_t)h) << 16);
}

// ---- fused prep: x->bf16 cast + LDS-tiled W transpose/cast + bias ----------
// bid < 8192            : x cast (4 floats/thread)
// bid in [8192, 8384)   : W 64x64 tile transpose (coalesced both sides)
// bid == 8384           : bias gather
__global__ void prep_kernel(const float* __restrict__ x,
                            const float* __restrict__ Wq, const float* __restrict__ Wk,
                            const float* __restrict__ Wv, const float* __restrict__ bq,
                            const float* __restrict__ bk, const float* __restrict__ bv,
                            ushort* __restrict__ xb, ushort* __restrict__ wt,
                            float* __restrict__ bias) {
  const int bid = blockIdx.x;
  const int tid = threadIdx.x;
  if (bid < 8192) {
    int i = bid * 256 + tid;
    float4 v = reinterpret_cast<const float4*>(x)[i];
    ushort4 o;
    o.x = f2bf(v.x); o.y = f2bf(v.y); o.z = f2bf(v.z); o.w = f2bf(v.w);
    reinterpret_cast<ushort4*>(xb)[i] = o;
  } else if (bid < 8384) {
    __shared__ ushort lds[64][66];        // 132B row stride = 33 words: conflict-free
    int w = bid - 8192;                   // 0..191
    int mat = w >> 6;                     // 0..2
    int rem = w & 63;
    int k0 = (rem >> 3) * 64;
    int n0 = (rem & 7) * 64;
    const float* W = (mat == 0) ? Wq : (mat == 1) ? Wk : Wv;
    int nn = tid & 63;
    #pragma unroll
    for (int r = 0; r < 16; ++r) {
      int kk = r * 4 + (tid >> 6);
      lds[kk][nn] = f2bf(W[(size_t)(k0 + kk) * 512 + n0 + nn]);  // coalesced read
    }
    __syncthreads();
    int kk2 = tid & 63;
    #pragma unroll
    for (int r = 0; r < 16; ++r) {
      int nn2 = r * 4 + (tid >> 6);
      wt[(size_t)(mat * 512 + n0 + nn2) * 512 + k0 + kk2] = lds[kk2][nn2];  // coalesced write
    }
  } else {
    #pragma unroll
    for (int e = 0; e < 6; ++e) {
      int n = tid * 6 + e;
      const float* bsrc = (n < 512) ? bq : (n < 1024) ? bk : bv;
      bias[n] = bsrc[n & 511];
    }
  }
}

// ---------------- GEMM (R4 body, lb(256,2)): 1 buffer, syncthreads ----------
// blocks 0..1023:    kv = xb @ [Wk|Wv]^T + b   (M=16384, N=1024)
// blocks 1024..1151: qc = gather(xb) @ Wq^T + b  (M=4040->4096, N=512)
__global__ __launch_bounds__(256, 2) void gemm_kernel(
    const ushort* __restrict__ xb, const ushort* __restrict__ wt,
    const float* __restrict__ bias, ushort* __restrict__ kv, ushort* __restrict__ qc) {
  __shared__ ushort As[128 * 64];         // 16 KB
  __shared__ ushort Bs[128 * 64];         // 16 KB

  const int tid = threadIdx.x;
  const int lane = tid & 63;
  const int wv = tid >> 6;
  const int bid = blockIdx.x;

  int m0, n0, ost, gather;
  const ushort* wtb;
  const float* biasb;
  ushort* outp;
  if (bid < 1024) {                       // kv partition, XCD swizzle within
    int swz = (bid & 7) * 128 + (bid >> 3);
    m0 = (swz >> 3) * 128; n0 = (swz & 7) * 128;
    wtb = wt + (size_t)512 * KDIM; biasb = bias + 512;
    outp = kv; ost = 1024; gather = 0;
  } else {                                // q partition, XCD swizzle within
    int b2 = bid - 1024;
    int swz = (b2 & 7) * 16 + (b2 >> 3);
    m0 = (swz >> 2) * 128; n0 = (swz & 3) * 128;
    wtb = wt; biasb = bias;
    outp = qc; ost = 512; gather = 1;
  }

  // per-thread staging sources (linear LDS dest + inverse-swizzled source col)
  const ushort* aSrc[4];
  const ushort* bSrc[4];
  #pragma unroll
  for (int i = 0; i < 4; ++i) {
    int boff = i * 4096 + wv * 1024 + lane * 16;   // linear byte off in 16 KB tile
    int row = boff >> 7;                           // 128 B per row
    int colb = boff & 127;
    int scol = (colb ^ ((row & 7) << 4)) >> 1;     // element col in [0,BK)
    size_t arow;
    if (gather) {
      int r = m0 + row;
      if (r > QROWS - 1) r = QROWS - 1;
      int bb = r / TOUT;
      int t2 = r - bb * TOUT;
      arow = (size_t)bb * TT + (size_t)t2 * 4 + FLT / 2;
    } else {
      arow = (size_t)(m0 + row);
    }
    aSrc[i] = xb + arow * KDIM + scol;
    bSrc[i] = wtb + (size_t)(n0 + row) * KDIM + scol;
  }

  const int fr = lane & 15;
  const int fq = lane >> 4;
  const int wr = wv >> 1;
  const int wc = wv & 1;

  f32x4 acc[4][4];
  #pragma unroll
  for (int i = 0; i < 4; ++i)
    #pragma unroll
    for (int j = 0; j < 4; ++j) acc[i][j] = (f32x4){0.f, 0.f, 0.f, 0.f};

  for (int t = 0; t < NT; ++t) {
    __syncthreads();
    const int koff = t * BK;
    #pragma unroll
    for (int i = 0; i < 4; ++i) {
      int ldst = i * 4096 + wv * 1024 + lane * 16;
      __builtin_amdgcn_global_load_lds(
          (const __attribute__((address_space(1))) unsigned int*)(aSrc[i] + koff),
          (__attribute__((address_space(3))) unsigned int*)((char*)As + ldst),
          16, 0, 0);
      __builtin_amdgcn_global_load_lds(
          (const __attribute__((address_space(1))) unsigned int*)(bSrc[i] + koff),
          (__attribute__((address_space(3))) unsigned int*)((char*)Bs + ldst),
          16, 0, 0);
    }
    __syncthreads();

    #pragma unroll
    for (int ks = 0; ks < 2; ++ks) {
      bf16x8 af[4], bg[4];
      #pragma unroll
      for (int i = 0; i < 4; ++i) {
        int ra = wr * 64 + i * 16 + fr;
        int ca = ks * 64 + fq * 16;                 // byte col
        af[i] = *reinterpret_cast<const bf16x8*>(
            (const char*)As + ra * 128 + (ca ^ ((ra & 7) << 4)));
        int rb = wc * 64 + i * 16 + fr;
        bg[i] = *reinterpret_cast<const bf16x8*>(
            (const char*)Bs + rb * 128 + (ca ^ ((rb & 7) << 4)));
      }
      #pragma unroll
      for (int i = 0; i < 4; ++i)
        #pragma unroll
        for (int j = 0; j < 4; ++j)
          acc[i][j] = __builtin_amdgcn_mfma_f32_16x16x32_bf16(af[i], bg[j], acc[i][j], 0, 0, 0);
    }
  }

  // epilogue: bias + bf16 store.  D: row=(lane>>4)*4+r, col=lane&15
  #pragma unroll
  for (int j = 0; j < 4; ++j) {
    int col = n0 + wc * 64 + j * 16 + fr;
    float bvl = biasb[col];
    #pragma unroll
    for (int i = 0; i < 4; ++i) {
      int rowb = m0 + wr * 64 + i * 16 + fq * 4;
      #pragma unroll
      for (int r = 0; r < 4; ++r) {
        if (!gather || (rowb + r) < QROWS)
          outp[(size_t)(rowb + r) * ost + col] = f2bf(acc[i][j][r] + bvl);
      }
    }
  }
}

// ---------------- windowed attention (R2-proven) ----------------
__global__ __launch_bounds__(256) void attn_kernel(
    const ushort* __restrict__ kv,   // [MROWS][1024] bf16: [k|v]
    const ushort* __restrict__ qc,   // [QROWS][512] bf16 (center q rows)
    float* __restrict__ out) {
  __shared__ float q_lds[KDIM];
  __shared__ float s_lds[FLT];
  __shared__ float p_lds[FLT];

  const int bid = blockIdx.x;
  const int b = bid & 7;                  // batch pinned to XCD (matches gemm)
  const int t = bid >> 3;
  const size_t base_row = (size_t)b * TT + (size_t)t * 4;
  const int tid = threadIdx.x;
  const int lane = tid & 63;
  const int wv = tid >> 6;

  {
    const ushort* qrow = qc + ((size_t)b * TOUT + t) * KDIM;
    uint v = *reinterpret_cast<const uint*>(qrow + tid * 2);
    q_lds[tid * 2]     = bf2f((ushort)(v & 0xffffu));
    q_lds[tid * 2 + 1] = bf2f((ushort)(v >> 16));
  }
  __syncthreads();

  // scores: 8 lanes per filter tap
  const int fl = lane >> 3;
  const int f = wv * 8 + fl;
  const int sub = lane & 7;
  const ushort* krow = kv + (base_row + f) * 1024;
  float acc = 0.f;
  #pragma unroll
  for (int j = 0; j < 8; ++j) {
    int d = (j * 8 + sub) * 8;
    uint4 kv4 = *reinterpret_cast<const uint4*>(krow + d);
    const ushort* ks = reinterpret_cast<const ushort*>(&kv4);
    #pragma unroll
    for (int e = 0; e < 8; ++e) acc += q_lds[d + e] * bf2f(ks[e]);
  }
  acc += __shfl_xor(acc, 1);
  acc += __shfl_xor(acc, 2);
  acc += __shfl_xor(acc, 4);
  if (sub == 0) s_lds[f] = acc * 0.04419417382415922f;  // 1/sqrt(512)
  __syncthreads();

  float m = -1e30f;
  #pragma unroll
  for (int i = 0; i < FLT; ++i) m = fmaxf(m, s_lds[i]);
  if (tid < FLT) p_lds[tid] = __expf(s_lds[tid] - m);
  __syncthreads();
  float sum = 0.f;
  #pragma unroll
  for (int i = 0; i < FLT; ++i) sum += p_lds[i];
  const float inv = 1.f / sum;

  const int d = tid * 2;
  float o0 = 0.f, o1 = 0.f;
  const ushort* vbase = kv + base_row * 1024 + 512 + d;
  #pragma unroll
  for (int ff = 0; ff < FLT; ++ff) {
    uint vvv = *reinterpret_cast<const uint*>(vbase + (size_t)ff * 1024);
    float w = p_lds[ff] * inv;
    o0 += w * bf2f((ushort)(vvv & 0xffffu));
    o1 += w * bf2f((ushort)(vvv >> 16));
  }
  float2* op = reinterpret_cast<float2*>(out + ((size_t)b * TOUT + t) * 512 + d);
  *op = make_float2(o0, o1);
}

// ---------------- launch ----------------
extern "C" void kernel_launch(void* const* d_in, const int* in_sizes, int n_in,
                              void* d_out, int out_size, void* d_ws, size_t ws_size,
                              hipStream_t stream) {
  const float* x  = (const float*)d_in[0];
  const float* Wq = (const float*)d_in[1];
  const float* bq = (const float*)d_in[2];
  const float* Wk = (const float*)d_in[3];
  const float* bk = (const float*)d_in[4];
  const float* Wv = (const float*)d_in[5];
  const float* bv = (const float*)d_in[6];
  float* out = (float*)d_out;

  char* ws = (char*)d_ws;
  ushort* xb   = (ushort*)ws;                                    // 16 MiB
  ushort* wt   = (ushort*)(ws + 16777216);                       // 1.5 MiB
  float*  bias = (float*)(ws + 16777216 + 1572864);              // 8 KiB
  ushort* kvb  = (ushort*)(ws + 18358272);                       // 32 MiB
  ushort* qc   = (ushort*)(ws + 18358272 + 33554432);            // 4 MiB

  hipLaunchKernelGGL(prep_kernel, dim3(8385), dim3(256), 0, stream,
                     x, Wq, Wk, Wv, bq, bk, bv, xb, wt, bias);
  hipLaunchKernelGGL(gemm_kernel, dim3(1152), dim3(256), 0, stream,
                     xb, wt, bias, kvb, qc);
  hipLaunchKernelGGL(attn_kernel, dim3(QROWS), dim3(256), 0, stream, kvb, qc, out);
}